// Round 1
// 1427.504 us; speedup vs baseline: 1.8857x; 1.8857x over previous
//
#include <hip/hip_runtime.h>
#include <hip/hip_bf16.h>
#include <stdint.h>

#define NN 200000
#define EE 200000
#define NB 196   // ceil(NN / 1024)

// ---------- helpers ----------
__device__ __forceinline__ short f2bf(float f) {
  union { float f; unsigned u; } a; a.f = f;
  unsigned r = a.u + 0x7fffu + ((a.u >> 16) & 1u);   // round-to-nearest-even
  return (short)(r >> 16);
}
__device__ __forceinline__ int pack2bf(float a, float b) {
  return (int)(((unsigned)(unsigned short)f2bf(a)) | ((unsigned)(unsigned short)f2bf(b) << 16));
}
__device__ __forceinline__ float bf2f(unsigned short s) {
  union { float f; unsigned u; } a; a.u = ((unsigned)s) << 16;
  return a.f;
}
__device__ __forceinline__ float sigm(float x) { return 1.f / (1.f + __expf(-x)); }
__device__ __forceinline__ float tanh_fast(float x) {
  x = fminf(fmaxf(x, -15.f), 15.f);
  float e = __expf(2.f * x);
  return (e - 1.f) / (e + 1.f);
}

using bf16x8 = __attribute__((ext_vector_type(8))) short;
using f32x4  = __attribute__((ext_vector_type(4))) float;

__device__ __forceinline__ void load_lds16(const void* g, void* l) {
  __builtin_amdgcn_global_load_lds((const __attribute__((address_space(1))) void*)g,
                                   (__attribute__((address_space(3))) void*)l, 16, 0, 0);
}

// ---------- CSR build: count -> scan (3 kernels) -> fill ----------
__global__ void count_kernel(const int* __restrict__ dst, int* __restrict__ counts) {
  int e = blockIdx.x * 256 + threadIdx.x;
  if (e < EE) atomicAdd(counts + dst[e], 1);
}

__global__ void scan_sums(const int* __restrict__ counts, int* __restrict__ bsum) {
  __shared__ int lds[256];
  int t = threadIdx.x, b = blockIdx.x;
  int base = b * 1024 + t * 4, s = 0;
#pragma unroll
  for (int i = 0; i < 4; ++i) { int idx = base + i; if (idx < NN) s += counts[idx]; }
  lds[t] = s; __syncthreads();
  for (int off = 128; off > 0; off >>= 1) {
    if (t < off) lds[t] += lds[t + off];
    __syncthreads();
  }
  if (t == 0) bsum[b] = lds[0];
}

__global__ void scan_blocks(const int* __restrict__ bsum, int* __restrict__ boff) {
  __shared__ int lds[256];
  int t = threadIdx.x;
  int v = (t < NB) ? bsum[t] : 0;
  lds[t] = v; __syncthreads();
  for (int off = 1; off < 256; off <<= 1) {
    int add = (t >= off) ? lds[t - off] : 0;
    __syncthreads();
    lds[t] += add;
    __syncthreads();
  }
  if (t < NB) boff[t] = lds[t] - v;                  // exclusive prefix of block sums
}

__global__ void scan_offsets(const int* __restrict__ counts, const int* __restrict__ boff,
                             int* __restrict__ offs) {
  __shared__ int lds[256];
  int t = threadIdx.x, b = blockIdx.x;
  int base = b * 1024 + t * 4;
  int c0 = (base     < NN) ? counts[base]     : 0;
  int c1 = (base + 1 < NN) ? counts[base + 1] : 0;
  int c2 = (base + 2 < NN) ? counts[base + 2] : 0;
  int c3 = (base + 3 < NN) ? counts[base + 3] : 0;
  int s = c0 + c1 + c2 + c3;
  lds[t] = s; __syncthreads();
  for (int off = 1; off < 256; off <<= 1) {
    int add = (t >= off) ? lds[t - off] : 0;
    __syncthreads();
    lds[t] += add;
    __syncthreads();
  }
  int run = boff[b] + lds[t] - s;                    // global exclusive prefix
  if (base     < NN) offs[base]     = run; run += c0;
  if (base + 1 < NN) offs[base + 1] = run; run += c1;
  if (base + 2 < NN) offs[base + 2] = run; run += c2;
  if (base + 3 < NN) offs[base + 3] = run;
}

__global__ void fill_kernel(const int* __restrict__ src, const int* __restrict__ dst,
                            const int* __restrict__ offs, int* __restrict__ cursor,
                            int* __restrict__ eidx) {
  int e = blockIdx.x * 256 + threadIdx.x;
  if (e < EE) {
    int d = dst[e];
    int p = offs[d] + atomicAdd(cursor + d, 1);
    eidx[p] = src[e];
  }
}

// ---------- gather + pack: one wave per node ----------
// Pulls children's h/c rows (coalesced 1KB row reads, no float atomics),
// writes c_sum f32 and the bf16 A row [x | h_sum] directly (pack_a fused away).
__global__ void gather_pack(const float* __restrict__ x, const float* __restrict__ h,
                            const float* __restrict__ c, const int* __restrict__ offs,
                            const int* __restrict__ eidx, short* __restrict__ A,
                            float* __restrict__ csum) {
  int gid = blockIdx.x * 256 + threadIdx.x;          // NN*64 threads exactly
  int n = gid >> 6, l = gid & 63;                    // wave-uniform n, lane l owns 4 floats
  int beg = offs[n];
  int end = (n == NN - 1) ? EE : offs[n + 1];
  float4 hs = {0.f, 0.f, 0.f, 0.f};
  float4 cs = {0.f, 0.f, 0.f, 0.f};
  for (int k = beg; k < end; ++k) {
    int s = eidx[k];
    const float4 hv = *(const float4*)(h + (size_t)s * 256 + l * 4);
    const float4 cv = *(const float4*)(c + (size_t)s * 256 + l * 4);
    hs.x += hv.x; hs.y += hv.y; hs.z += hv.z; hs.w += hv.w;
    cs.x += cv.x; cs.y += cv.y; cs.z += cv.z; cs.w += cv.w;
  }
  *(float4*)(csum + (size_t)n * 256 + l * 4) = cs;
  const float4 xv = *(const float4*)(x + (size_t)n * 256 + l * 4);
  int2 xo, ho;
  xo.x = pack2bf(xv.x, xv.y); xo.y = pack2bf(xv.z, xv.w);
  ho.x = pack2bf(hs.x, hs.y); ho.y = pack2bf(hs.z, hs.w);
  *(int2*)(A + (size_t)n * 512 + l * 4)       = xo;  // x half
  *(int2*)(A + (size_t)n * 512 + 256 + l * 4) = ho;  // h_sum half
}

// ---------- pack B^T [1024,512] bf16, columns interleaved p=4j+{i,o,u,f}; bias[1024] ----------
__global__ void pack_b_kernel(const float* __restrict__ W_iou, const float* __restrict__ U_iou,
                              const float* __restrict__ b_iou, const float* __restrict__ U_f_w,
                              const float* __restrict__ U_f_b,
                              short* __restrict__ Bp, float* __restrict__ biasp) {
  int idx = blockIdx.x * 256 + threadIdx.x;          // 1024*512
  if (idx >= 1024 * 512) return;
  int p = idx >> 9, k = idx & 511;
  int j = p >> 2, comp = p & 3;
  float v;
  if (comp < 3) v = (k < 256) ? W_iou[(size_t)(comp * 256 + j) * 256 + k]
                              : U_iou[(size_t)(comp * 256 + j) * 256 + (k - 256)];
  else          v = (k < 256) ? 0.f : U_f_w[(size_t)j * 256 + (k - 256)];
  Bp[(size_t)p * 512 + k] = f2bf(v);
  if (k == 0) biasp[p] = (comp < 3) ? b_iou[comp * 256 + j] : U_f_b[j];
}

// ---------- fused GEMM [N,512]x[512,1024]^T + gate epilogue ----------
__global__ __launch_bounds__(256)
void gemm_fused(const short* __restrict__ A, const short* __restrict__ Bp,
                const float* __restrict__ biasp,
                float* __restrict__ outh, float* __restrict__ outc) {
  __shared__ short smem[16384];                      // 32 KB: sA[128][64] + sB[128][64]; reused as Y[128][128]
  short* sA = smem;
  short* sB = smem + 8192;

  const int tid  = threadIdx.x;
  const int lane = tid & 63;
  const int wave = tid >> 6;
  const int wm = wave >> 1, wn = wave & 1;           // 2x2 waves, each 64x64
  const int row16 = lane & 15, quad = lane >> 4;

  const int mbase = blockIdx.y * 128;
  const int nbase = blockIdx.x * 128;
  const int wbase = wave * 64;

  f32x4 acc[4][4];
#pragma unroll
  for (int i = 0; i < 4; ++i)
#pragma unroll
    for (int j = 0; j < 4; ++j)
      acc[i][j] = (f32x4){0.f, 0.f, 0.f, 0.f};

  for (int kt = 0; kt < 512; kt += 64) {
#pragma unroll
    for (int i = 0; i < 4; ++i) {
      int s = i * 256 + tid;                         // 0..1023 : 16B segment id
      int r = s >> 3, seg = s & 7;
      int ra = mbase + r; if (ra > NN - 1) ra = NN - 1;
      const short* gA = A  + (size_t)ra * 512 + kt + seg * 8;
      const short* gB = Bp + (size_t)(nbase + r) * 512 + kt + seg * 8;
      load_lds16(gA, sA + (i * 256 + wbase) * 8);    // wave-uniform LDS base + lane*16
      load_lds16(gB, sB + (i * 256 + wbase) * 8);
    }
    __syncthreads();
#pragma unroll
    for (int kk = 0; kk < 64; kk += 32) {
      bf16x8 af[4], bfr[4];
#pragma unroll
      for (int mi = 0; mi < 4; ++mi)
        af[mi] = *(const bf16x8*)(sA + (wm * 64 + mi * 16 + row16) * 64 + kk + quad * 8);
#pragma unroll
      for (int ni = 0; ni < 4; ++ni)
        bfr[ni] = *(const bf16x8*)(sB + (wn * 64 + ni * 16 + row16) * 64 + kk + quad * 8);
#pragma unroll
      for (int mi = 0; mi < 4; ++mi)
#pragma unroll
        for (int ni = 0; ni < 4; ++ni)
          acc[mi][ni] = __builtin_amdgcn_mfma_f32_16x16x32_bf16(af[mi], bfr[ni], acc[mi][ni], 0, 0, 0);
    }
    __syncthreads();
  }

  // ---- epilogue: bias, bf16 LDS round-trip to regroup (i,o,u,f), gates ----
  float biasv[4];
#pragma unroll
  for (int ni = 0; ni < 4; ++ni)
    biasv[ni] = biasp[nbase + wn * 64 + ni * 16 + row16];

  short* Y = smem;                                   // [128][128] bf16
#pragma unroll
  for (int mi = 0; mi < 4; ++mi)
#pragma unroll
    for (int ni = 0; ni < 4; ++ni)
#pragma unroll
      for (int r = 0; r < 4; ++r) {
        int lrow = wm * 64 + mi * 16 + quad * 4 + r; // C/D: row=(lane>>4)*4+reg, col=lane&15
        int lcol = wn * 64 + ni * 16 + row16;
        Y[lrow * 128 + lcol] = f2bf(acc[mi][ni][r] + biasv[ni]);
      }
  __syncthreads();

  const int jbase = nbase >> 2;                      // 32 gate-columns per block
#pragma unroll
  for (int t = 0; t < 16; ++t) {
    int u2 = t * 256 + tid;                          // 0..4095 = 128 rows x 32 j
    int row = u2 >> 5, jj = u2 & 31;
    int grow = mbase + row;
    if (grow < NN) {
      const unsigned short* yp = (const unsigned short*)Y + row * 128 + jj * 4;
      ushort4 y4 = *(const ushort4*)yp;              // (i,o,u,f) for one j
      float iv = bf2f(y4.x), ov = bf2f(y4.y), uv = bf2f(y4.z), fv = bf2f(y4.w);
      size_t off = (size_t)grow * 256 + (jbase + jj);
      float csum = outc[off];                        // c_sum lives here; same thread overwrites
      float cnew = sigm(iv) * tanh_fast(uv) + sigm(fv) * csum;
      float hnew = sigm(ov) * tanh_fast(cnew);
      outh[off] = hnew;
      outc[off] = cnew;
    }
  }
}

// ---------- launch ----------
extern "C" void kernel_launch(void* const* d_in, const int* in_sizes, int n_in,
                              void* d_out, int out_size, void* d_ws, size_t ws_size,
                              hipStream_t stream) {
  const float* x     = (const float*)d_in[0];
  const float* h     = (const float*)d_in[1];
  const float* c     = (const float*)d_in[2];
  const int*   src   = (const int*)d_in[3];
  const int*   dst   = (const int*)d_in[4];
  const float* W_iou = (const float*)d_in[5];
  const float* U_iou = (const float*)d_in[6];
  const float* b_iou = (const float*)d_in[7];
  const float* U_f_w = (const float*)d_in[8];
  const float* U_f_b = (const float*)d_in[9];

  float* outh = (float*)d_out;                 // h_new (final); holds int CSR scratch until epilogue
  float* outc = outh + (size_t)NN * 256;       // c_new (final); holds c_sum from gather until epilogue

  short* A     = (short*)d_ws;                 // [N,512] bf16 = 204.8 MB
  short* Bp    = A + (size_t)NN * 512;         // [1024,512] bf16 = 1 MB
  float* biasp = (float*)(Bp + 1024 * 512);    // [1024] f32

  // CSR scratch lives in the outh half of d_out (~4 MB of 204.8 MB);
  // fully dead before gemm_fused's epilogue overwrites outh.
  int* scratch = (int*)d_out;
  int* counts  = scratch;                      // [N]
  int* cursor  = scratch + NN;                 // [N]
  int* eidx    = scratch + 2 * NN;             // [E]
  int* offs    = scratch + 2 * NN + EE;        // [N]
  int* bsum    = scratch + 3 * NN + EE;        // [NB]
  int* boff    = bsum + NB;                    // [NB]

  hipMemsetAsync(scratch, 0, (size_t)(2 * NN) * sizeof(int), stream);  // counts + cursor

  count_kernel <<<(EE + 255) / 256, 256, 0, stream>>>(dst, counts);
  scan_sums    <<<NB, 256, 0, stream>>>(counts, bsum);
  scan_blocks  <<<1, 256, 0, stream>>>(bsum, boff);
  scan_offsets <<<NB, 256, 0, stream>>>(counts, boff, offs);
  fill_kernel  <<<(EE + 255) / 256, 256, 0, stream>>>(src, dst, offs, cursor, eidx);
  gather_pack  <<<(NN * 64) / 256, 256, 0, stream>>>(x, h, c, offs, eidx, A, outc);
  pack_b_kernel<<<(1024 * 512) / 256, 256, 0, stream>>>(W_iou, U_iou, b_iou, U_f_w, U_f_b, Bp, biasp);
  gemm_fused   <<<dim3(8, 1563), 256, 0, stream>>>(A, Bp, biasp, outh, outc);
}

// Round 3
// 1298.800 us; speedup vs baseline: 2.0726x; 1.0991x over previous
//
#include <hip/hip_runtime.h>
#include <hip/hip_bf16.h>
#include <stdint.h>

#define NN 200000
#define EE 200000
#define NB 196   // ceil(NN / 1024)

// ---------- helpers ----------
__device__ __forceinline__ short f2bf(float f) {
  union { float f; unsigned u; } a; a.f = f;
  unsigned r = a.u + 0x7fffu + ((a.u >> 16) & 1u);   // round-to-nearest-even
  return (short)(r >> 16);
}
__device__ __forceinline__ int pack2bf(float a, float b) {
  return (int)(((unsigned)(unsigned short)f2bf(a)) | ((unsigned)(unsigned short)f2bf(b) << 16));
}
__device__ __forceinline__ float bf2f(unsigned short s) {
  union { float f; unsigned u; } a; a.u = ((unsigned)s) << 16;
  return a.f;
}
__device__ __forceinline__ float sigm(float x) { return 1.f / (1.f + __expf(-x)); }
__device__ __forceinline__ float tanh_fast(float x) {
  x = fminf(fmaxf(x, -15.f), 15.f);
  float e = __expf(2.f * x);
  return (e - 1.f) / (e + 1.f);
}

using bf16x8 = __attribute__((ext_vector_type(8))) short;
using f32x4  = __attribute__((ext_vector_type(4))) float;

__device__ __forceinline__ void load_lds16(const void* g, void* l) {
  __builtin_amdgcn_global_load_lds((const __attribute__((address_space(1))) void*)g,
                                   (__attribute__((address_space(3))) void*)l, 16, 0, 0);
}

// ---------- CSR build: count -> scan (3 kernels) -> fill ----------
__global__ void count_kernel(const int* __restrict__ dst, int* __restrict__ counts) {
  int e = blockIdx.x * 256 + threadIdx.x;
  if (e < EE) atomicAdd(counts + dst[e], 1);
}

__global__ void scan_sums(const int* __restrict__ counts, int* __restrict__ bsum) {
  __shared__ int lds[256];
  int t = threadIdx.x, b = blockIdx.x;
  int base = b * 1024 + t * 4, s = 0;
#pragma unroll
  for (int i = 0; i < 4; ++i) { int idx = base + i; if (idx < NN) s += counts[idx]; }
  lds[t] = s; __syncthreads();
  for (int off = 128; off > 0; off >>= 1) {
    if (t < off) lds[t] += lds[t + off];
    __syncthreads();
  }
  if (t == 0) bsum[b] = lds[0];
}

__global__ void scan_blocks(const int* __restrict__ bsum, int* __restrict__ boff) {
  __shared__ int lds[256];
  int t = threadIdx.x;
  int v = (t < NB) ? bsum[t] : 0;
  lds[t] = v; __syncthreads();
  for (int off = 1; off < 256; off <<= 1) {
    int add = (t >= off) ? lds[t - off] : 0;
    __syncthreads();
    lds[t] += add;
    __syncthreads();
  }
  if (t < NB) boff[t] = lds[t] - v;                  // exclusive prefix of block sums
}

__global__ void scan_offsets(const int* __restrict__ counts, const int* __restrict__ boff,
                             int* __restrict__ offs) {
  __shared__ int lds[256];
  int t = threadIdx.x, b = blockIdx.x;
  int base = b * 1024 + t * 4;
  int c0 = (base     < NN) ? counts[base]     : 0;
  int c1 = (base + 1 < NN) ? counts[base + 1] : 0;
  int c2 = (base + 2 < NN) ? counts[base + 2] : 0;
  int c3 = (base + 3 < NN) ? counts[base + 3] : 0;
  int s = c0 + c1 + c2 + c3;
  lds[t] = s; __syncthreads();
  for (int off = 1; off < 256; off <<= 1) {
    int add = (t >= off) ? lds[t - off] : 0;
    __syncthreads();
    lds[t] += add;
    __syncthreads();
  }
  int run = boff[b] + lds[t] - s;                    // global exclusive prefix
  if (base     < NN) offs[base]     = run; run += c0;
  if (base + 1 < NN) offs[base + 1] = run; run += c1;
  if (base + 2 < NN) offs[base + 2] = run; run += c2;
  if (base + 3 < NN) offs[base + 3] = run;
}

__global__ void fill_kernel(const int* __restrict__ src, const int* __restrict__ dst,
                            const int* __restrict__ offs, int* __restrict__ cursor,
                            int* __restrict__ eidx) {
  int e = blockIdx.x * 256 + threadIdx.x;
  if (e < EE) {
    int d = dst[e];
    int p = offs[d] + atomicAdd(cursor + d, 1);
    eidx[p] = src[e];
  }
}

// ---------- gather + pack: one wave per node ----------
__global__ void gather_pack(const float* __restrict__ x, const float* __restrict__ h,
                            const float* __restrict__ c, const int* __restrict__ offs,
                            const int* __restrict__ eidx, short* __restrict__ A,
                            float* __restrict__ csum) {
  int gid = blockIdx.x * 256 + threadIdx.x;          // NN*64 threads exactly
  int n = gid >> 6, l = gid & 63;                    // wave-uniform n, lane l owns 4 floats
  int beg = offs[n];
  int end = (n == NN - 1) ? EE : offs[n + 1];
  float4 hs = {0.f, 0.f, 0.f, 0.f};
  float4 cs = {0.f, 0.f, 0.f, 0.f};
  for (int k = beg; k < end; ++k) {
    int s = eidx[k];
    const float4 hv = *(const float4*)(h + (size_t)s * 256 + l * 4);
    const float4 cv = *(const float4*)(c + (size_t)s * 256 + l * 4);
    hs.x += hv.x; hs.y += hv.y; hs.z += hv.z; hs.w += hv.w;
    cs.x += cv.x; cs.y += cv.y; cs.z += cv.z; cs.w += cv.w;
  }
  *(float4*)(csum + (size_t)n * 256 + l * 4) = cs;
  const float4 xv = *(const float4*)(x + (size_t)n * 256 + l * 4);
  int2 xo, ho;
  xo.x = pack2bf(xv.x, xv.y); xo.y = pack2bf(xv.z, xv.w);
  ho.x = pack2bf(hs.x, hs.y); ho.y = pack2bf(hs.z, hs.w);
  *(int2*)(A + (size_t)n * 512 + l * 4)       = xo;  // x half
  *(int2*)(A + (size_t)n * 512 + 256 + l * 4) = ho;  // h_sum half
}

// ---------- pack B^T [1024,512] bf16, columns interleaved p=4j+{i,o,u,f}; bias[1024] ----------
__global__ void pack_b_kernel(const float* __restrict__ W_iou, const float* __restrict__ U_iou,
                              const float* __restrict__ b_iou, const float* __restrict__ U_f_w,
                              const float* __restrict__ U_f_b,
                              short* __restrict__ Bp, float* __restrict__ biasp) {
  int idx = blockIdx.x * 256 + threadIdx.x;          // 1024*512
  if (idx >= 1024 * 512) return;
  int p = idx >> 9, k = idx & 511;
  int j = p >> 2, comp = p & 3;
  float v;
  if (comp < 3) v = (k < 256) ? W_iou[(size_t)(comp * 256 + j) * 256 + k]
                              : U_iou[(size_t)(comp * 256 + j) * 256 + (k - 256)];
  else          v = (k < 256) ? 0.f : U_f_w[(size_t)j * 256 + (k - 256)];
  Bp[(size_t)p * 512 + k] = f2bf(v);
  if (k == 0) biasp[p] = (comp < 3) ? b_iou[comp * 256 + j] : U_f_b[j];
}

// ---------- fused GEMM [N,512]x[512,1024]^T + gate epilogue ----------
// 128x128 tile, 4 waves. Double-buffered LDS (2x32KB), depth-1 prefetch with
// counted vmcnt(8) across raw s_barriers (T3/T4 minimum-2-phase), XOR-swizzled
// LDS (T2, both-sides: pre-swizzled global source + swizzled ds_read), and
// XCD-grouped block mapping (each XCD owns contiguous M-panels x all 8 N-blocks).
__global__ __launch_bounds__(256)
void gemm_fused(const short* __restrict__ A, const short* __restrict__ Bp,
                const float* __restrict__ biasp,
                float* __restrict__ outh, float* __restrict__ outc) {
  __shared__ short smem[32768];                      // 64 KB: 2 x (sA[128][64] + sB[128][64]); buf0 reused as Y[128][128]

  const int tid  = threadIdx.x;
  const int lane = tid & 63;
  const int wave = tid >> 6;
  const int wm = wave >> 1, wn = wave & 1;           // 2x2 waves, each 64x64
  const int row16 = lane & 15, quad = lane >> 4;
  const int rx = row16 & 7;                          // read-side swizzle key

  // XCD-grouped mapping: lin%8 = XCD (HW round-robin); each XCD sweeps
  // contiguous M-panels, 8 N-blocks per panel back-to-back (A panel stays in its L2).
  const int lin = blockIdx.x;
  const int xcd = lin & 7;
  const int t8  = lin >> 3;                          // 0..1567
  const int mp  = xcd * 196 + (t8 >> 3);             // M-panel
  const int nb  = t8 & 7;                            // N-block
  const int mbase = mp * 128;
  const int nbase = nb * 128;
  if (mbase >= NN) return;                           // 40 dead pad blocks (whole block exits)

  const int wbase = wave * 64;

  f32x4 acc[4][4];
#pragma unroll
  for (int i = 0; i < 4; ++i)
#pragma unroll
    for (int j = 0; j < 4; ++j)
      acc[i][j] = (f32x4){0.f, 0.f, 0.f, 0.f};

  // Bias loaded and force-completed BEFORE any staging: keeps the counted-vmcnt
  // window (tile loads only) provably clean of other VMEM ops.
  float biasv[4];
#pragma unroll
  for (int ni = 0; ni < 4; ++ni) {
    biasv[ni] = biasp[nbase + wn * 64 + ni * 16 + row16];
    asm volatile("" :: "v"(biasv[ni]));              // keep-alive: force issue+complete here
  }

  // loop-invariant staging addresses; global source pre-swizzled so the linear
  // global_load_lds dest yields LDS[r][seg] = global (r, seg ^ (r&7))
  const short* gAb[4];
  const short* gBb[4];
#pragma unroll
  for (int i = 0; i < 4; ++i) {
    int s = i * 256 + tid;                           // 16B segment id 0..1023
    int r = s >> 3, seg = s & 7;
    int sseg = seg ^ (r & 7);
    int ra = mbase + r; if (ra > NN - 1) ra = NN - 1;
    gAb[i] = A  + (size_t)ra * 512 + sseg * 8;
    gBb[i] = Bp + (size_t)(nbase + r) * 512 + sseg * 8;
  }

  // prologue: stage tile 0 into buf0
#pragma unroll
  for (int i = 0; i < 4; ++i) {
    load_lds16(gAb[i], smem + (i * 256 + wbase) * 8);
    load_lds16(gBb[i], smem + 8192 + (i * 256 + wbase) * 8);
  }

  for (int t = 0; t < 8; ++t) {
    if (t < 7) {                                     // issue next tile, keep it in flight
      const int kt = (t + 1) * 64;
      short* db = smem + ((t + 1) & 1) * 16384;
#pragma unroll
      for (int i = 0; i < 4; ++i) {
        load_lds16(gAb[i] + kt, db + (i * 256 + wbase) * 8);
        load_lds16(gBb[i] + kt, db + 8192 + (i * 256 + wbase) * 8);
      }
      asm volatile("s_waitcnt vmcnt(8)" ::: "memory");   // cur tile's 8 loads done; next 8 in flight
    } else {
      asm volatile("s_waitcnt vmcnt(0)" ::: "memory");
    }
    __builtin_amdgcn_sched_barrier(0);
    __builtin_amdgcn_s_barrier();                    // cur buf ready for all waves
    __builtin_amdgcn_sched_barrier(0);

    const short* sAc = smem + (t & 1) * 16384;
    const short* sBc = sAc + 8192;
#pragma unroll
    for (int kk = 0; kk < 64; kk += 32) {
      const int K8 = kk >> 3;                        // 0 or 4
      bf16x8 af[4], bfr[4];
#pragma unroll
      for (int mi = 0; mi < 4; ++mi)
        af[mi] = *(const bf16x8*)(sAc + (wm * 64 + mi * 16 + row16) * 64 + (((K8 + quad) ^ rx)) * 8);
#pragma unroll
      for (int ni = 0; ni < 4; ++ni)
        bfr[ni] = *(const bf16x8*)(sBc + (wn * 64 + ni * 16 + row16) * 64 + (((K8 + quad) ^ rx)) * 8);
#pragma unroll
      for (int mi = 0; mi < 4; ++mi)
#pragma unroll
        for (int ni = 0; ni < 4; ++ni)
          acc[mi][ni] = __builtin_amdgcn_mfma_f32_16x16x32_bf16(af[mi], bfr[ni], acc[mi][ni], 0, 0, 0);
    }
    __builtin_amdgcn_sched_barrier(0);
    __builtin_amdgcn_s_barrier();                    // all waves done reading cur buf
    __builtin_amdgcn_sched_barrier(0);
  }

  // ---- epilogue: bias, bf16 LDS round-trip to regroup (i,o,u,f), gates ----
  short* Y = smem;                                   // [128][128] bf16 = 32 KB (buf0; safe after closing barrier)
#pragma unroll
  for (int mi = 0; mi < 4; ++mi)
#pragma unroll
    for (int ni = 0; ni < 4; ++ni)
#pragma unroll
      for (int r = 0; r < 4; ++r) {
        int lrow = wm * 64 + mi * 16 + quad * 4 + r; // C/D: row=(lane>>4)*4+reg, col=lane&15
        int lcol = wn * 64 + ni * 16 + row16;
        Y[lrow * 128 + lcol] = f2bf(acc[mi][ni][r] + biasv[ni]);
      }
  __syncthreads();

  const int jbase = nbase >> 2;                      // 32 gate-columns per block
#pragma unroll
  for (int t = 0; t < 16; ++t) {
    int u2 = t * 256 + tid;                          // 0..4095 = 128 rows x 32 j
    int row = u2 >> 5, jj = u2 & 31;
    int grow = mbase + row;
    if (grow < NN) {
      const unsigned short* yp = (const unsigned short*)Y + row * 128 + jj * 4;
      ushort4 y4 = *(const ushort4*)yp;              // (i,o,u,f) for one j
      float iv = bf2f(y4.x), ov = bf2f(y4.y), uv = bf2f(y4.z), fv = bf2f(y4.w);
      size_t off = (size_t)grow * 256 + (jbase + jj);
      float csum = outc[off];                        // c_sum lives here; same thread overwrites
      float cnew = sigm(iv) * tanh_fast(uv) + sigm(fv) * csum;
      float hnew = sigm(ov) * tanh_fast(cnew);
      outh[off] = hnew;
      outc[off] = cnew;
    }
  }
}

// ---------- launch ----------
extern "C" void kernel_launch(void* const* d_in, const int* in_sizes, int n_in,
                              void* d_out, int out_size, void* d_ws, size_t ws_size,
                              hipStream_t stream) {
  const float* x     = (const float*)d_in[0];
  const float* h     = (const float*)d_in[1];
  const float* c     = (const float*)d_in[2];
  const int*   src   = (const int*)d_in[3];
  const int*   dst   = (const int*)d_in[4];
  const float* W_iou = (const float*)d_in[5];
  const float* U_iou = (const float*)d_in[6];
  const float* b_iou = (const float*)d_in[7];
  const float* U_f_w = (const float*)d_in[8];
  const float* U_f_b = (const float*)d_in[9];

  float* outh = (float*)d_out;                 // h_new (final); holds int CSR scratch until epilogue
  float* outc = outh + (size_t)NN * 256;       // c_new (final); holds c_sum from gather until epilogue

  short* A     = (short*)d_ws;                 // [N,512] bf16 = 204.8 MB
  short* Bp    = A + (size_t)NN * 512;         // [1024,512] bf16 = 1 MB
  float* biasp = (float*)(Bp + 1024 * 512);    // [1024] f32

  // CSR scratch lives in the outh half of d_out (~4 MB of 204.8 MB);
  // fully dead before gemm_fused's epilogue overwrites outh.
  int* scratch = (int*)d_out;
  int* counts  = scratch;                      // [N]
  int* cursor  = scratch + NN;                 // [N]
  int* eidx    = scratch + 2 * NN;             // [E]
  int* offs    = scratch + 2 * NN + EE;        // [N]
  int* bsum    = scratch + 3 * NN + EE;        // [NB]
  int* boff    = bsum + NB;                    // [NB]

  hipMemsetAsync(scratch, 0, (size_t)(2 * NN) * sizeof(int), stream);  // counts + cursor

  count_kernel <<<(EE + 255) / 256, 256, 0, stream>>>(dst, counts);
  scan_sums    <<<NB, 256, 0, stream>>>(counts, bsum);
  scan_blocks  <<<1, 256, 0, stream>>>(bsum, boff);
  scan_offsets <<<NB, 256, 0, stream>>>(counts, boff, offs);
  fill_kernel  <<<(EE + 255) / 256, 256, 0, stream>>>(src, dst, offs, cursor, eidx);
  gather_pack  <<<(NN * 64) / 256, 256, 0, stream>>>(x, h, c, offs, eidx, A, outc);
  pack_b_kernel<<<(1024 * 512) / 256, 256, 0, stream>>>(W_iou, U_iou, b_iou, U_f_w, U_f_b, Bp, biasp);
  gemm_fused   <<<8 * 196 * 8, 256, 0, stream>>>(A, Bp, biasp, outh, outc);   // 12544 blocks, XCD-grouped
}